// Round 7
// baseline (82.246 us; speedup 1.0000x reference)
//
#include <hip/hip_runtime.h>

// KaolinRenderer: coverage-mask rasterizer.
// Output = repeat(mask[B,H,W], 3) — the reference z-buffer is dead code.
//
// BIT-EXACTNESS IS CRITICAL: mask is binary, threshold 2e-2. Faces with
// w-clamped vertices (|ndc| ~1e8) have catastrophically-cancelling edge
// functions whose sign is rounding-determined. We mirror the numpy reference's
// float32 op order exactly and disable FMA contraction for every value that
// feeds the exact inside-test. Skipping faces once a pixel is covered is safe
// (sticky OR); changing per-face exact-test arithmetic is not.
//
// R13: SCREEN-WIDE CLASSIFY + COMPACT. Evidence: R10 (+aggregate => +dur),
// R12 (tail critical path /8, dur unchanged) => raster is AGGREGATE-work
// bound. The aggregate is 2048 tiles x 4096 faces of cull + survivors.
// But w-clamped faces (|ndc|~1e8) are globally decidable ONCE: their edge
// functions are sign-near-constant over the whole screen (|e|~1e16 >> err
// ~1e3 and >> cross-screen variation ~1e8). So face_pack now runs the SAME
// R4-validated conservative test against the FULL-SCREEN rect:
//   - certified-out (some edge < -err AND some edge > +err screen-wide):
//     face contributes to NO tile => dropped from the list entirely.
//   - all three edges certified > err (or all < -err) screen-wide: face
//     covers EVERY pixel => per-batch all-covered flag (sound: reference
//     e_i > 0 (resp < 0) at every pixel => inside true).
//   - else: appended to a compacted list via global atomicAdd. Order is
//     arbitrary — coverage is an order-independent sticky OR.
// Raster (R8's one-wave-per-tile shape, best measured) scans only cnt[b]
// faces with a tail-lane validity guard. Group count, L2 face re-read
// traffic, and survivor count all scale by (1-D), D = dropped fraction.
// Counters zeroed via 16-byte hipMemsetAsync (graph-capturable, like the
// harness's own fillBuffer).
// R8: cull data (A,B,C,err) hoisted to face_pack; midpoint-spread cull (FMA
// allowed in cull only; err has ~2^8 slack); survivor eval uses stored A=dx,
// B=-dy: e = A*(py-ya) + B*(px-xa) IEEE-identical to reference
// dx*(py-ya) - dy*(px-xa) ((-a)*b == -(a*b), x+(-w) == x-w).
// R6/R7: register cull + ballot compaction; readlane broadcast (k from
// __ballot is wave-uniform -> scalar file).

#pragma clang fp contract(off)

#define HW      256
#define BATCH   2
#define VCOUNT  4096
#define FCOUNT  4096
#define NTILES  1024          // 32x32 tiles of 8x8 per batch
#define CULL_EPS 1.52587890625e-05f   // 2^-16

__global__ __launch_bounds__(256)
void face_pack_kernel(const float* __restrict__ verts,
                      const int* __restrict__ faces,
                      const float* __restrict__ R,
                      const float* __restrict__ T,
                      float4* __restrict__ fxy4,   // [B*F] (x0,y0,x1,y1) compacted
                      float2* __restrict__ fxy2,   // [B*F] (x2,y2)       compacted
                      float4* __restrict__ ed0,    // [B*F] (A,B,C,err)   compacted
                      float4* __restrict__ ed1,
                      float4* __restrict__ ed2,
                      unsigned* __restrict__ meta) // [0..1]=cnt/batch [2..3]=allcover
{
#pragma clang fp contract(off)
    int gid = blockIdx.x * blockDim.x + threadIdx.x;
    if (gid >= BATCH * FCOUNT) return;
    int b = gid / FCOUNT;

    const float fproj = 1.7320508075688772f;   // 1/tan(30deg), f64->f32 like numpy

    const float* Rb = R + b * 9;
    const float* Tb = T + b * 3;

    // t_i = -((Rt[i][0]*T0 + Rt[i][1]*T1) + Rt[i][2]*T2), Rt[i][j] = R[j][i]
    float t0 = -((Rb[0*3+0]*Tb[0] + Rb[1*3+0]*Tb[1]) + Rb[2*3+0]*Tb[2]);
    float t1 = -((Rb[0*3+1]*Tb[0] + Rb[1*3+1]*Tb[1]) + Rb[2*3+1]*Tb[2]);
    float t2 = -((Rb[0*3+2]*Tb[0] + Rb[1*3+2]*Tb[1]) + Rb[2*3+2]*Tb[2]);

    // VP rows 0 (x), 1 (y), 3 (w) only.
    float VP00 = fproj * Rb[0*3+0], VP01 = fproj * Rb[1*3+0],
          VP02 = fproj * Rb[2*3+0], VP03 = fproj * t0;
    float VP10 = fproj * Rb[0*3+1], VP11 = fproj * Rb[1*3+1],
          VP12 = fproj * Rb[2*3+1], VP13 = fproj * t1;
    float VP30 = -Rb[0*3+2], VP31 = -Rb[1*3+2],
          VP32 = -Rb[2*3+2], VP33 = -t2;

    const int* fp = faces + (size_t)gid * 3;
    float xs[3], ys[3];
#pragma unroll
    for (int j = 0; j < 3; ++j) {
        const float* vv = verts + ((size_t)b * VCOUNT + fp[j]) * 3;
        float vx = vv[0], vy = vv[1], vz = vv[2];
        // Identical op sequence to the reference einsum (sequential adds),
        // contract off => bit-identical NDC for every reference to a vertex.
        float cx = ((vx*VP00 + vy*VP01) + vz*VP02) + VP03;
        float cy = ((vx*VP10 + vy*VP11) + vz*VP12) + VP13;
        float cw = ((vx*VP30 + vy*VP31) + vz*VP32) + VP33;
        float w = fmaxf(cw, 1e-8f);
        xs[j] = cx / w;
        ys[j] = cy / w;
    }

    // Diffs: same f32 ops as the reference's (x1-x0) etc.
    float d01x = xs[1] - xs[0], d01y = ys[1] - ys[0];
    float d12x = xs[2] - xs[1], d12y = ys[2] - ys[1];
    float d20x = xs[0] - xs[2], d20y = ys[0] - ys[2];

    // Per-edge linear model of the reference edge function:
    //   e ~= A*py + B*px + C,  A = dx, B = -dy, C = dy*xa - dx*ya
    // err bounds |model - reference_e| over [-1,1]^2 incl. reference rounding
    // (R4-validated formula, unchanged).
    float A0 = d01x, B0 = -d01y, C0 = d01y * xs[0] - d01x * ys[0];
    float A1 = d12x, B1 = -d12y, C1 = d12y * xs[1] - d12x * ys[1];
    float A2 = d20x, B2 = -d20y, C2 = d20y * xs[2] - d20x * ys[2];
    float e0r = CULL_EPS * (fabsf(d01x) * (1.0f + fabsf(ys[0]))
                          + fabsf(d01y) * (1.0f + fabsf(xs[0])));
    float e1r = CULL_EPS * (fabsf(d12x) * (1.0f + fabsf(ys[1]))
                          + fabsf(d12y) * (1.0f + fabsf(xs[1])));
    float e2r = CULL_EPS * (fabsf(d20x) * (1.0f + fabsf(ys[2]))
                          + fabsf(d20y) * (1.0f + fabsf(xs[2])));

    // ---- Screen-wide classification (same validated test, full-screen rect).
    // Screen rect corners use the exact raster pixel formula (monotone):
    float pxlo = ((0.0f   + 0.5f) / 256.0f) * 2.0f - 1.0f;
    float pxhi = ((255.0f + 0.5f) / 256.0f) * 2.0f - 1.0f;
    float xm = 0.5f * (pxlo + pxhi), xr = 0.5f * (pxhi - pxlo);
    float ym = xm, yr = xr;   // square screen, same formula in y

    float sb0 = A0 * ym + B0 * xm + C0;
    float ss0 = fabsf(A0) * yr + fabsf(B0) * xr;
    float sb1 = A1 * ym + B1 * xm + C1;
    float ss1 = fabsf(A1) * yr + fabsf(B1) * xr;
    float sb2 = A2 * ym + B2 * xm + C2;
    float ss2 = fabsf(A2) * yr + fabsf(B2) * xr;
    bool cn0 = (sb0 + ss0 < -e0r), cp0 = (sb0 - ss0 > e0r);
    bool cn1 = (sb1 + ss1 < -e1r), cp1 = (sb1 - ss1 > e1r);
    bool cn2 = (sb2 + ss2 < -e2r), cp2 = (sb2 - ss2 > e2r);

    bool killneg = cn0 || cn1 || cn2;     // some edge < 0 everywhere
    bool killpos = cp0 || cp1 || cp2;     // some edge > 0 everywhere
    if (killneg && killpos) return;       // contributes to NO pixel: drop

    if ((cp0 && cp1 && cp2) || (cn0 && cn1 && cn2)) {
        // inside == true at EVERY pixel (all e>0 or all e<0, certified).
        atomicOr(&meta[2 + b], 1u);
        return;
    }

    unsigned ci = atomicAdd(&meta[b], 1u);
    size_t o = (size_t)b * FCOUNT + ci;
    fxy4[o] = make_float4(xs[0], ys[0], xs[1], ys[1]);
    fxy2[o] = make_float2(xs[2], ys[2]);
    ed0[o] = make_float4(A0, B0, C0, e0r);
    ed1[o] = make_float4(A1, B1, C1, e1r);
    ed2[o] = make_float4(A2, B2, C2, e2r);
}

// Wave-uniform broadcast through the scalar file (v_readlane_b32).
__device__ __forceinline__ float bcast_lane(float v, int k) {
    return __int_as_float(__builtin_amdgcn_readlane(__float_as_int(v), k));
}

__global__ __launch_bounds__(64)
void raster_kernel(const float4* __restrict__ ed0,
                   const float4* __restrict__ ed1,
                   const float4* __restrict__ ed2,
                   const float4* __restrict__ fxy4,
                   const float2* __restrict__ fxy2,
                   const unsigned* __restrict__ meta,
                   float* __restrict__ out)
{
#pragma clang fp contract(off)
    int b    = blockIdx.y;
    int tile = blockIdx.x;                 // 32x32 tiles of 8x8 over 256x256
    int qx = (tile & 31) << 3;
    int qy = (tile >> 5) << 3;
    int lane = threadIdx.x;                // one wave per block
    int px_i = qx + (lane & 7);
    int py_i = qy + (lane >> 3);

    // Same formula as reference: ((i + 0.5)/W)*2 - 1
    float px = (((float)px_i + 0.5f) / 256.0f) * 2.0f - 1.0f;
    float py = (((float)py_i + 0.5f) / 256.0f) * 2.0f - 1.0f;

    // This wave's 8x8 rect (pixel formula is monotone in index).
    float pxlo = (((float)qx       + 0.5f) / 256.0f) * 2.0f - 1.0f;
    float pxhi = (((float)(qx + 7) + 0.5f) / 256.0f) * 2.0f - 1.0f;
    float pylo = (((float)qy       + 0.5f) / 256.0f) * 2.0f - 1.0f;
    float pyhi = (((float)(qy + 7) + 0.5f) / 256.0f) * 2.0f - 1.0f;
    // Midpoint/half-extent form: for linear f = A*py+B*px+C,
    // max/min over rect = base +/- (|A|*yr + |B|*xr). Cull-only arithmetic.
    float xm = 0.5f * (pxlo + pxhi), xr = 0.5f * (pxhi - pxlo);
    float ym = 0.5f * (pylo + pyhi), yr = 0.5f * (pyhi - pylo);

    const float4* e0p = ed0  + (size_t)b * FCOUNT;
    const float4* e1p = ed1  + (size_t)b * FCOUNT;
    const float4* e2p = ed2  + (size_t)b * FCOUNT;
    const float4* f4  = fxy4 + (size_t)b * FCOUNT;
    const float2* f2  = fxy2 + (size_t)b * FCOUNT;

    int cnt = (int)meta[b];
    // All-covering face exists: every pixel inside, certified screen-wide.
    bool covered = (meta[2 + b] != 0u);

    for (int g = 0; g < cnt; g += 64) {
        if (__all((int)covered)) break;

        int idx = g + lane;
        bool valid = idx < cnt;
        int li = valid ? idx : (cnt - 1);   // cnt >= 1 here (g < cnt)
        float4 E0 = e0p[li];
        float4 E1 = e1p[li];
        float4 E2 = e2p[li];
        float4 q0 = f4[li];
        float2 q1 = f2[li];

        // Conservative cull. Skippable iff some edge certifies e<0 over the
        // whole rect AND some edge certifies e>0 (kills both sign branches of
        // `inside`). FMA allowed here: it only tightens the cull's own
        // rounding, and err has ~2^8 slack over f32 eps by construction.
        bool killneg = false, killpos = false;
        {
#pragma clang fp contract(fast)
            float b0 = E0.x * ym + E0.y * xm + E0.z;
            float s0 = fabsf(E0.x) * yr + fabsf(E0.y) * xr;
            killneg = killneg || (b0 + s0 < -E0.w);
            killpos = killpos || (b0 - s0 >  E0.w);
            float b1 = E1.x * ym + E1.y * xm + E1.z;
            float s1 = fabsf(E1.x) * yr + fabsf(E1.y) * xr;
            killneg = killneg || (b1 + s1 < -E1.w);
            killpos = killpos || (b1 - s1 >  E1.w);
            float b2 = E2.x * ym + E2.y * xm + E2.z;
            float s2 = fabsf(E2.x) * yr + fabsf(E2.y) * xr;
            killneg = killneg || (b2 + s2 < -E2.w);
            killpos = killpos || (b2 - s2 >  E2.w);
        }
        bool skip = !valid || (killneg && killpos);

        // Survivor loop: broadcast lane-k values via v_readlane (k is
        // wave-uniform). No memory ops inside.
        unsigned long long m = __ballot((int)!skip);
        while (m) {
            int k = __ffsll((long long)m) - 1;
            m &= m - 1;
            float A0 = bcast_lane(E0.x, k), B0 = bcast_lane(E0.y, k);
            float A1 = bcast_lane(E1.x, k), B1 = bcast_lane(E1.y, k);
            float A2 = bcast_lane(E2.x, k), B2 = bcast_lane(E2.y, k);
            float ax0 = bcast_lane(q0.x, k), ay0 = bcast_lane(q0.y, k);
            float ax1 = bcast_lane(q0.z, k), ay1 = bcast_lane(q0.w, k);
            float ax2 = bcast_lane(q1.x, k), ay2 = bcast_lane(q1.y, k);
            // e = A*(py-ya) + B*(px-xa), A=dx, B=-dy: bit-identical to the
            // reference dx*(py-ya) - dy*(px-xa) since (-a)*b == -(a*b) and
            // x+(-w) == x-w in IEEE f32. Contract off => no FMA.
            float e0 = A0 * (py - ay0) + B0 * (px - ax0);
            float e1 = A1 * (py - ay1) + B1 * (px - ax1);
            float e2 = A2 * (py - ay2) + B2 * (px - ax2);
            float mn = fminf(fminf(e0, e1), e2);
            float mx = fmaxf(fmaxf(e0, e1), e2);
            covered = covered || (mn >= 0.0f) || (mx <= 0.0f);
        }
    }

    float val = covered ? 1.0f : 0.0f;
    size_t o = ((size_t)(b * HW + py_i) * HW + px_i) * 3;
    out[o + 0] = val;
    out[o + 1] = val;
    out[o + 2] = val;
}

extern "C" void kernel_launch(void* const* d_in, const int* in_sizes, int n_in,
                              void* d_out, int out_size, void* d_ws, size_t ws_size,
                              hipStream_t stream) {
    const float* verts = (const float*)d_in[0];   // [2,4096,3] f32
    const int*   faces = (const int*)d_in[1];     // [2,4096,3] i32
    const float* R     = (const float*)d_in[2];   // [2,3,3]    f32
    const float* T     = (const float*)d_in[3];   // [2,3]      f32
    float*       out   = (float*)d_out;           // [2,256,256,3] f32

    float4* fxy4 = (float4*)d_ws;                        // 128 KiB
    float2* fxy2 = (float2*)(fxy4 + BATCH * FCOUNT);     // 64 KiB
    float4* ed0  = (float4*)(fxy2 + BATCH * FCOUNT);     // 128 KiB
    float4* ed1  = ed0 + BATCH * FCOUNT;                 // 128 KiB
    float4* ed2  = ed1 + BATCH * FCOUNT;                 // 128 KiB
    unsigned* meta = (unsigned*)(ed2 + BATCH * FCOUNT);  // 16 B

    hipMemsetAsync(meta, 0, 4 * sizeof(unsigned), stream);

    int nf = BATCH * FCOUNT;
    face_pack_kernel<<<(nf + 255) / 256, 256, 0, stream>>>(verts, faces, R, T,
                                                           fxy4, fxy2,
                                                           ed0, ed1, ed2, meta);

    dim3 grid(NTILES, BATCH);
    raster_kernel<<<grid, 64, 0, stream>>>(ed0, ed1, ed2, fxy4, fxy2, meta, out);
}

// Round 8
// 75.696 us; speedup vs baseline: 1.0865x; 1.0865x over previous
//
#include <hip/hip_runtime.h>

// KaolinRenderer: coverage-mask rasterizer.
// Output = repeat(mask[B,H,W], 3) — the reference z-buffer is dead code.
//
// BIT-EXACTNESS IS CRITICAL: mask is binary, threshold 2e-2. Faces with
// w-clamped vertices (|ndc| ~1e8) have catastrophically-cancelling edge
// functions whose sign is rounding-determined. We mirror the numpy reference's
// float32 op order exactly and disable FMA contraction for every value that
// feeds the exact inside-test. Skipping faces once a pixel is covered is safe
// (sticky OR); changing per-face exact-test arithmetic is not.
//
// R14: R13's classify+compact, with the two real fixes:
//  (1) WAVE-AGGREGATED compaction. R13 funneled 8192 same-address atomicAdds
//      into 2 counters (~+18 µs, the whole regression). Now: one ballot +
//      one lane-0 atomicAdd per wave per counter (256 atomics total), lane
//      slot via popc(mask & below). Stores become wave-contiguous.
//  (2) BIG-FACES-FIRST ordering (legal: coverage is an order-independent
//      sticky OR — reordering changes only when early-exit fires, never the
//      value). Faces with any |coord|>8 are w-clamp garbage (~1e8 edges):
//      vs any 8x8 rect they are either certified-skipped (rect outside,
//      margin ~1e16 >> err) or instantly rect-covering (rect inside => all
//      edges certified same sign, one survivor eval covers all 64 px). They
//      are compacted DESCENDING from the array top; raster scans the big
//      region first => interior tiles terminate in their first group(s).
//  Raster uses the best-measured shape (R7: 256 thr, 4 waves, 8x8 quadrant
//  each, 62.8 µs) + tail-guarded loops over the two compacted regions.
//  R13 evidence kept: screen-wide classification is sound (absmax 0); no
//  face covers the whole screen (allcover never fired) but the flag stays.
// R8: cull data (A,B,C,err) hoisted to pack; midpoint-spread cull (FMA in
// cull only; err has ~2^8 slack); survivor eval uses stored A=dx, B=-dy:
// e = A*(py-ya) + B*(px-xa) IEEE-identical to reference dx*(py-ya) -
// dy*(px-xa) ((-a)*b == -(a*b), x+(-w) == x-w).
// R6/R7: register cull + ballot compaction; readlane broadcast (k from
// __ballot is wave-uniform -> scalar file).

#pragma clang fp contract(off)

#define HW      256
#define BATCH   2
#define VCOUNT  4096
#define FCOUNT  4096
#define CULL_EPS 1.52587890625e-05f   // 2^-16
#define BIGTHR   8.0f

// meta layout: [0..1] cnt_normal per batch, [2..3] allcover, [4..5] cnt_big
__global__ __launch_bounds__(256)
void face_pack_kernel(const float* __restrict__ verts,
                      const int* __restrict__ faces,
                      const float* __restrict__ R,
                      const float* __restrict__ T,
                      float4* __restrict__ fxy4,   // [B*F] (x0,y0,x1,y1)
                      float2* __restrict__ fxy2,   // [B*F] (x2,y2)
                      float4* __restrict__ ed0,    // [B*F] (A,B,C,err)
                      float4* __restrict__ ed1,
                      float4* __restrict__ ed2,
                      unsigned* __restrict__ meta)
{
#pragma clang fp contract(off)
    int gid = blockIdx.x * blockDim.x + threadIdx.x;   // grid exactly B*F
    int b = gid / FCOUNT;                              // block-uniform
    int lane = threadIdx.x & 63;

    const float fproj = 1.7320508075688772f;   // 1/tan(30deg), f64->f32 like numpy

    const float* Rb = R + b * 9;
    const float* Tb = T + b * 3;

    // t_i = -((Rt[i][0]*T0 + Rt[i][1]*T1) + Rt[i][2]*T2), Rt[i][j] = R[j][i]
    float t0 = -((Rb[0*3+0]*Tb[0] + Rb[1*3+0]*Tb[1]) + Rb[2*3+0]*Tb[2]);
    float t1 = -((Rb[0*3+1]*Tb[0] + Rb[1*3+1]*Tb[1]) + Rb[2*3+1]*Tb[2]);
    float t2 = -((Rb[0*3+2]*Tb[0] + Rb[1*3+2]*Tb[1]) + Rb[2*3+2]*Tb[2]);

    // VP rows 0 (x), 1 (y), 3 (w) only.
    float VP00 = fproj * Rb[0*3+0], VP01 = fproj * Rb[1*3+0],
          VP02 = fproj * Rb[2*3+0], VP03 = fproj * t0;
    float VP10 = fproj * Rb[0*3+1], VP11 = fproj * Rb[1*3+1],
          VP12 = fproj * Rb[2*3+1], VP13 = fproj * t1;
    float VP30 = -Rb[0*3+2], VP31 = -Rb[1*3+2],
          VP32 = -Rb[2*3+2], VP33 = -t2;

    const int* fp = faces + (size_t)gid * 3;
    float xs[3], ys[3];
#pragma unroll
    for (int j = 0; j < 3; ++j) {
        const float* vv = verts + ((size_t)b * VCOUNT + fp[j]) * 3;
        float vx = vv[0], vy = vv[1], vz = vv[2];
        // Identical op sequence to the reference einsum (sequential adds),
        // contract off => bit-identical NDC for every reference to a vertex.
        float cx = ((vx*VP00 + vy*VP01) + vz*VP02) + VP03;
        float cy = ((vx*VP10 + vy*VP11) + vz*VP12) + VP13;
        float cw = ((vx*VP30 + vy*VP31) + vz*VP32) + VP33;
        float w = fmaxf(cw, 1e-8f);
        xs[j] = cx / w;
        ys[j] = cy / w;
    }

    // Diffs: same f32 ops as the reference's (x1-x0) etc.
    float d01x = xs[1] - xs[0], d01y = ys[1] - ys[0];
    float d12x = xs[2] - xs[1], d12y = ys[2] - ys[1];
    float d20x = xs[0] - xs[2], d20y = ys[0] - ys[2];

    // Per-edge linear model: e ~= A*py + B*px + C; A=dx, B=-dy,
    // C = dy*xa - dx*ya. err bounds |model - reference_e| over [-1,1]^2
    // incl. reference rounding (R4-validated formula, unchanged).
    float A0 = d01x, B0 = -d01y, C0 = d01y * xs[0] - d01x * ys[0];
    float A1 = d12x, B1 = -d12y, C1 = d12y * xs[1] - d12x * ys[1];
    float A2 = d20x, B2 = -d20y, C2 = d20y * xs[2] - d20x * ys[2];
    float e0r = CULL_EPS * (fabsf(d01x) * (1.0f + fabsf(ys[0]))
                          + fabsf(d01y) * (1.0f + fabsf(xs[0])));
    float e1r = CULL_EPS * (fabsf(d12x) * (1.0f + fabsf(ys[1]))
                          + fabsf(d12y) * (1.0f + fabsf(xs[1])));
    float e2r = CULL_EPS * (fabsf(d20x) * (1.0f + fabsf(ys[2]))
                          + fabsf(d20y) * (1.0f + fabsf(xs[2])));

    // Screen-wide classification (R13-validated: same conservative test,
    // full-screen rect, corners from the exact raster pixel formula).
    float pxlo = ((0.0f   + 0.5f) / 256.0f) * 2.0f - 1.0f;
    float pxhi = ((255.0f + 0.5f) / 256.0f) * 2.0f - 1.0f;
    float xm = 0.5f * (pxlo + pxhi), xr = 0.5f * (pxhi - pxlo);
    float ym = xm, yr = xr;   // square screen, same formula in y

    float sb0 = A0 * ym + B0 * xm + C0, ss0 = fabsf(A0) * yr + fabsf(B0) * xr;
    float sb1 = A1 * ym + B1 * xm + C1, ss1 = fabsf(A1) * yr + fabsf(B1) * xr;
    float sb2 = A2 * ym + B2 * xm + C2, ss2 = fabsf(A2) * yr + fabsf(B2) * xr;
    bool cn0 = (sb0 + ss0 < -e0r), cp0 = (sb0 - ss0 > e0r);
    bool cn1 = (sb1 + ss1 < -e1r), cp1 = (sb1 - ss1 > e1r);
    bool cn2 = (sb2 + ss2 < -e2r), cp2 = (sb2 - ss2 > e2r);

    bool drop = (cn0 || cn1 || cn2) && (cp0 || cp1 || cp2); // no pixel inside
    bool allc = !drop && ((cp0 && cp1 && cp2) || (cn0 && cn1 && cn2));
    if (allc) atomicOr(&meta[2 + b], 1u);   // every pixel inside, certified

    bool keep = !drop && !allc;
    bool bigf = false;
#pragma unroll
    for (int j = 0; j < 3; ++j)
        bigf = bigf || (fabsf(xs[j]) > BIGTHR) || (fabsf(ys[j]) > BIGTHR);

    bool nrm = keep && !bigf;
    bool big = keep && bigf;

    // Wave-aggregated two-segment compaction: ONE atomic per wave per
    // counter (lane 0), slot = base + popc(mask & lanes-below).
    unsigned long long mN = __ballot((int)nrm);
    unsigned long long mB = __ballot((int)big);
    unsigned tN = 0u, tB = 0u;
    if (lane == 0) {
        unsigned nN = (unsigned)__popcll(mN);
        unsigned nB = (unsigned)__popcll(mB);
        if (nN) tN = atomicAdd(&meta[b],     nN);
        if (nB) tB = atomicAdd(&meta[4 + b], nB);
    }
    unsigned baseN = (unsigned)__shfl((int)tN, 0);
    unsigned baseB = (unsigned)__shfl((int)tB, 0);
    unsigned long long below = (lane == 0) ? 0ull : (~0ull >> (64 - lane));

    if (nrm || big) {
        size_t o;
        if (nrm) {
            unsigned ci = baseN + (unsigned)__popcll(mN & below);
            o = (size_t)b * FCOUNT + ci;                  // ascending from 0
        } else {
            unsigned ci = baseB + (unsigned)__popcll(mB & below);
            o = (size_t)b * FCOUNT + (FCOUNT - 1 - ci);   // descending from top
        }
        fxy4[o] = make_float4(xs[0], ys[0], xs[1], ys[1]);
        fxy2[o] = make_float2(xs[2], ys[2]);
        ed0[o] = make_float4(A0, B0, C0, e0r);
        ed1[o] = make_float4(A1, B1, C1, e1r);
        ed2[o] = make_float4(A2, B2, C2, e2r);
    }
}

// Wave-uniform broadcast through the scalar file (v_readlane_b32).
__device__ __forceinline__ float bcast_lane(float v, int k) {
    return __int_as_float(__builtin_amdgcn_readlane(__float_as_int(v), k));
}

__global__ __launch_bounds__(256)
void raster_kernel(const float4* __restrict__ ed0,
                   const float4* __restrict__ ed1,
                   const float4* __restrict__ ed2,
                   const float4* __restrict__ fxy4,
                   const float2* __restrict__ fxy2,
                   const unsigned* __restrict__ meta,
                   float* __restrict__ out)
{
#pragma clang fp contract(off)
    int b    = blockIdx.y;
    int tile = blockIdx.x;                       // 16x16 tiles over 256x256
    int tx = (tile & 15) << 4;
    int ty = (tile >> 4) << 4;

    // R7 shape (best measured): 4 waves, each owns an 8x8 quadrant.
    int wave = threadIdx.x >> 6;
    int lane = threadIdx.x & 63;
    int qx = tx + ((wave & 1) << 3);
    int qy = ty + ((wave >> 1) << 3);
    int px_i = qx + (lane & 7);
    int py_i = qy + (lane >> 3);

    // Same formula as reference: ((i + 0.5)/W)*2 - 1
    float px = (((float)px_i + 0.5f) / 256.0f) * 2.0f - 1.0f;
    float py = (((float)py_i + 0.5f) / 256.0f) * 2.0f - 1.0f;

    // The wave's 8x8 rect (pixel formula is monotone in index).
    float pxlo = (((float)qx       + 0.5f) / 256.0f) * 2.0f - 1.0f;
    float pxhi = (((float)(qx + 7) + 0.5f) / 256.0f) * 2.0f - 1.0f;
    float pylo = (((float)qy       + 0.5f) / 256.0f) * 2.0f - 1.0f;
    float pyhi = (((float)(qy + 7) + 0.5f) / 256.0f) * 2.0f - 1.0f;
    float xm = 0.5f * (pxlo + pxhi), xr = 0.5f * (pxhi - pxlo);
    float ym = 0.5f * (pylo + pyhi), yr = 0.5f * (pyhi - pylo);

    const float4* e0p = ed0  + (size_t)b * FCOUNT;
    const float4* e1p = ed1  + (size_t)b * FCOUNT;
    const float4* e2p = ed2  + (size_t)b * FCOUNT;
    const float4* f4  = fxy4 + (size_t)b * FCOUNT;
    const float2* f2  = fxy2 + (size_t)b * FCOUNT;

    int cntN = (int)meta[b];
    int nbig = (int)meta[4 + b];
    bool covered = (meta[2 + b] != 0u);   // certified screen-covering face

    // Two regions: big faces [FCOUNT-nbig, FCOUNT) FIRST, then [0, cntN).
#pragma unroll 1
    for (int region = 0; region < 2; ++region) {
        int lo = region ? 0    : (FCOUNT - nbig);
        int hi = region ? cntN : FCOUNT;
        for (int g = lo; g < hi; g += 64) {
            if (__all((int)covered)) break;

            int idx = g + lane;
            bool valid = idx < hi;
            int li = valid ? idx : (hi - 1);   // region nonempty if loop entered
            float4 E0 = e0p[li];
            float4 E1 = e1p[li];
            float4 E2 = e2p[li];
            float4 q0 = f4[li];
            float2 q1 = f2[li];

            // Conservative cull. Skippable iff some edge certifies e<0 over
            // the rect AND some certifies e>0 (kills both sign branches of
            // `inside`). FMA allowed here only; err has ~2^8 slack.
            bool killneg = false, killpos = false;
            {
#pragma clang fp contract(fast)
                float b0 = E0.x * ym + E0.y * xm + E0.z;
                float s0 = fabsf(E0.x) * yr + fabsf(E0.y) * xr;
                killneg = killneg || (b0 + s0 < -E0.w);
                killpos = killpos || (b0 - s0 >  E0.w);
                float b1 = E1.x * ym + E1.y * xm + E1.z;
                float s1 = fabsf(E1.x) * yr + fabsf(E1.y) * xr;
                killneg = killneg || (b1 + s1 < -E1.w);
                killpos = killpos || (b1 - s1 >  E1.w);
                float b2 = E2.x * ym + E2.y * xm + E2.z;
                float s2 = fabsf(E2.x) * yr + fabsf(E2.y) * xr;
                killneg = killneg || (b2 + s2 < -E2.w);
                killpos = killpos || (b2 - s2 >  E2.w);
            }
            bool skip = !valid || (killneg && killpos);

            // Survivor loop: broadcast lane-k values via v_readlane (k is
            // wave-uniform). No memory ops inside.
            unsigned long long m = __ballot((int)!skip);
            while (m) {
                int k = __ffsll((long long)m) - 1;
                m &= m - 1;
                float A0 = bcast_lane(E0.x, k), B0 = bcast_lane(E0.y, k);
                float A1 = bcast_lane(E1.x, k), B1 = bcast_lane(E1.y, k);
                float A2 = bcast_lane(E2.x, k), B2 = bcast_lane(E2.y, k);
                float ax0 = bcast_lane(q0.x, k), ay0 = bcast_lane(q0.y, k);
                float ax1 = bcast_lane(q0.z, k), ay1 = bcast_lane(q0.w, k);
                float ax2 = bcast_lane(q1.x, k), ay2 = bcast_lane(q1.y, k);
                // e = A*(py-ya) + B*(px-xa), A=dx, B=-dy: bit-identical to
                // the reference dx*(py-ya) - dy*(px-xa) ((-a)*b == -(a*b),
                // x+(-w) == x-w in IEEE f32). Contract off => no FMA.
                float e0 = A0 * (py - ay0) + B0 * (px - ax0);
                float e1 = A1 * (py - ay1) + B1 * (px - ax1);
                float e2 = A2 * (py - ay2) + B2 * (px - ax2);
                float mn = fminf(fminf(e0, e1), e2);
                float mx = fmaxf(fmaxf(e0, e1), e2);
                covered = covered || (mn >= 0.0f) || (mx <= 0.0f);
            }
        }
    }

    float val = covered ? 1.0f : 0.0f;
    size_t o = ((size_t)(b * HW + py_i) * HW + px_i) * 3;
    out[o + 0] = val;
    out[o + 1] = val;
    out[o + 2] = val;
}

extern "C" void kernel_launch(void* const* d_in, const int* in_sizes, int n_in,
                              void* d_out, int out_size, void* d_ws, size_t ws_size,
                              hipStream_t stream) {
    const float* verts = (const float*)d_in[0];   // [2,4096,3] f32
    const int*   faces = (const int*)d_in[1];     // [2,4096,3] i32
    const float* R     = (const float*)d_in[2];   // [2,3,3]    f32
    const float* T     = (const float*)d_in[3];   // [2,3]      f32
    float*       out   = (float*)d_out;           // [2,256,256,3] f32

    float4* fxy4 = (float4*)d_ws;                        // 128 KiB
    float2* fxy2 = (float2*)(fxy4 + BATCH * FCOUNT);     // 64 KiB
    float4* ed0  = (float4*)(fxy2 + BATCH * FCOUNT);     // 128 KiB
    float4* ed1  = ed0 + BATCH * FCOUNT;                 // 128 KiB
    float4* ed2  = ed1 + BATCH * FCOUNT;                 // 128 KiB
    unsigned* meta = (unsigned*)(ed2 + BATCH * FCOUNT);  // 24 B

    hipMemsetAsync(meta, 0, 6 * sizeof(unsigned), stream);

    int nf = BATCH * FCOUNT;
    face_pack_kernel<<<nf / 256, 256, 0, stream>>>(verts, faces, R, T,
                                                   fxy4, fxy2,
                                                   ed0, ed1, ed2, meta);

    dim3 grid(256, BATCH);
    raster_kernel<<<grid, 256, 0, stream>>>(ed0, ed1, ed2, fxy4, fxy2, meta, out);
}

// Round 9
// 63.556 us; speedup vs baseline: 1.2941x; 1.1910x over previous
//
#include <hip/hip_runtime.h>

// KaolinRenderer: coverage-mask rasterizer.
// Output = repeat(mask[B,H,W], 3) — the reference z-buffer is dead code.
//
// BIT-EXACTNESS IS CRITICAL: mask is binary, threshold 2e-2. Faces with
// w-clamped vertices (|ndc| ~1e8) have catastrophically-cancelling edge
// functions whose sign is rounding-determined. We mirror the numpy reference's
// float32 op order exactly and disable FMA contraction. Skipping faces once
// `covered` is true is safe (sticky OR); changing per-face arithmetic is not.
//
// R15 = R7 VERBATIM REVERT (session champion, 62.85 µs measured round 1).
// Evidence from R8-R14: dur ≈ 40 µs unconditional harness ws-fill + ~3 µs
// pack + ~20 µs issue-bound raster. The raster term is dominated by GENUINE
// survivor evals: ~87% of faces have >=1 w-clamped vertex; their edge lines
// cross the screen and survive any conservative rect cull in the ~2-tile
// bands along those lines. Readlane broadcast (zero latency) is near-optimal
// for those evals. Every structural change lost: R10 scan-split (+10),
// R11 fusion (+6), R12 phased tail (+6), R13 compaction w/ serial atomics
// (+19), R14 wave-aggregated compaction + big-first (+13). R7 is a sharp
// local optimum at the harness floor.
//
// R7 structure: face_pack writes 6 NDC coords/face (24B). Raster: 4 waves
// per 16x16 tile, each wave owns an 8x8 quadrant; per-lane register cull
// (R4-validated conservative half-plane interval test), ballot-compact,
// survivors broadcast via v_readlane (k from __ballot is wave-uniform ->
// scalar file, no LDS-pipe ops); per-lane diff recompute after broadcast is
// bit-exact (same f32 operands, same ops as the reference's broadcast).

#pragma clang fp contract(off)

#define HW      256
#define BATCH   2
#define VCOUNT  4096
#define FCOUNT  4096
#define CULL_EPS 1.52587890625e-05f   // 2^-16

__global__ __launch_bounds__(256)
void face_pack_kernel(const float* __restrict__ verts,
                      const int* __restrict__ faces,
                      const float* __restrict__ R,
                      const float* __restrict__ T,
                      float4* __restrict__ fxy4,   // [B*F] (x0,y0,x1,y1)
                      float2* __restrict__ fxy2)   // [B*F] (x2,y2)
{
#pragma clang fp contract(off)
    int gid = blockIdx.x * blockDim.x + threadIdx.x;
    if (gid >= BATCH * FCOUNT) return;
    int b = gid / FCOUNT;

    const float fproj = 1.7320508075688772f;   // 1/tan(30deg), f64->f32 like numpy

    const float* Rb = R + b * 9;
    const float* Tb = T + b * 3;

    // t_i = -((Rt[i][0]*T0 + Rt[i][1]*T1) + Rt[i][2]*T2), Rt[i][j] = R[j][i]
    float t0 = -((Rb[0*3+0]*Tb[0] + Rb[1*3+0]*Tb[1]) + Rb[2*3+0]*Tb[2]);
    float t1 = -((Rb[0*3+1]*Tb[0] + Rb[1*3+1]*Tb[1]) + Rb[2*3+1]*Tb[2]);
    float t2 = -((Rb[0*3+2]*Tb[0] + Rb[1*3+2]*Tb[1]) + Rb[2*3+2]*Tb[2]);

    // VP rows 0 (x), 1 (y), 3 (w) only.
    float VP00 = fproj * Rb[0*3+0], VP01 = fproj * Rb[1*3+0],
          VP02 = fproj * Rb[2*3+0], VP03 = fproj * t0;
    float VP10 = fproj * Rb[0*3+1], VP11 = fproj * Rb[1*3+1],
          VP12 = fproj * Rb[2*3+1], VP13 = fproj * t1;
    float VP30 = -Rb[0*3+2], VP31 = -Rb[1*3+2],
          VP32 = -Rb[2*3+2], VP33 = -t2;

    const int* fp = faces + (size_t)gid * 3;
    float xs[3], ys[3];
#pragma unroll
    for (int j = 0; j < 3; ++j) {
        const float* vv = verts + ((size_t)b * VCOUNT + fp[j]) * 3;
        float vx = vv[0], vy = vv[1], vz = vv[2];
        // Identical op sequence to the reference einsum (sequential adds),
        // contract off => bit-identical NDC for every reference to a vertex.
        float cx = ((vx*VP00 + vy*VP01) + vz*VP02) + VP03;
        float cy = ((vx*VP10 + vy*VP11) + vz*VP12) + VP13;
        float cw = ((vx*VP30 + vy*VP31) + vz*VP32) + VP33;
        float w = fmaxf(cw, 1e-8f);
        xs[j] = cx / w;
        ys[j] = cy / w;
    }

    fxy4[gid] = make_float4(xs[0], ys[0], xs[1], ys[1]);
    fxy2[gid] = make_float2(xs[2], ys[2]);
}

// Wave-uniform broadcast through the scalar file (v_readlane_b32).
__device__ __forceinline__ float bcast_lane(float v, int k) {
    return __int_as_float(__builtin_amdgcn_readlane(__float_as_int(v), k));
}

__global__ __launch_bounds__(256)
void raster_kernel(const float4* __restrict__ fxy4,
                   const float2* __restrict__ fxy2,
                   float* __restrict__ out)
{
#pragma clang fp contract(off)
    int b    = blockIdx.y;
    int tile = blockIdx.x;                       // 16x16 tiles over 256x256
    int tx = (tile & 15) << 4;
    int ty = (tile >> 4) << 4;

    // 8x8 quadrant per wave (tighter cull rect than 16x4).
    int wave = threadIdx.x >> 6;
    int lane = threadIdx.x & 63;
    int qx = tx + ((wave & 1) << 3);
    int qy = ty + ((wave >> 1) << 3);
    int px_i = qx + (lane & 7);
    int py_i = qy + (lane >> 3);

    // Same formula as reference: ((i + 0.5)/W)*2 - 1
    float px = (((float)px_i + 0.5f) / 256.0f) * 2.0f - 1.0f;
    float py = (((float)py_i + 0.5f) / 256.0f) * 2.0f - 1.0f;

    // This wave's 8x8 rect (pixel formula is monotone in index).
    float pxlo = (((float)qx       + 0.5f) / 256.0f) * 2.0f - 1.0f;
    float pxhi = (((float)(qx + 7) + 0.5f) / 256.0f) * 2.0f - 1.0f;
    float pylo = (((float)qy       + 0.5f) / 256.0f) * 2.0f - 1.0f;
    float pyhi = (((float)(qy + 7) + 0.5f) / 256.0f) * 2.0f - 1.0f;

    const float4* f4 = fxy4 + (size_t)b * FCOUNT;
    const float2* f2 = fxy2 + (size_t)b * FCOUNT;

    bool covered = false;

    for (int g = 0; g < FCOUNT; g += 64) {
        if (__all((int)covered)) break;

        // Phase 1: lane owns face g+lane; coalesced 24B load, all-register cull.
        float4 q0 = f4[g + lane];
        float2 q1 = f2[g + lane];
        float x0 = q0.x, y0 = q0.y, x1 = q0.z, y1 = q0.w;
        float x2 = q1.x, y2 = q1.y;
        // Diffs: same ops as the reference's broadcast (x1-x0) etc.
        float d01x = x1 - x0, d01y = y1 - y0;
        float d12x = x2 - x1, d12y = y2 - y1;
        float d20x = x0 - x2, d20y = y0 - y2;

        // Conservative cull: e(p) ~= A*py + B*px + C over the wave rect.
        // Skippable iff some edge certifies e<0 everywhere AND some edge
        // certifies e>0 everywhere (kills both sign branches of `inside`).
        bool killneg = false, killpos = false;
        {
            float A[3]  = { d01x, d12x, d20x };
            float Bc[3] = { -d01y, -d12y, -d20y };
            float xa[3] = { x0, x1, x2 };
            float ya[3] = { y0, y1, y2 };
#pragma unroll
            for (int e = 0; e < 3; ++e) {
                float C = (-Bc[e]) * xa[e] - A[e] * ya[e];
                float err = CULL_EPS * (fabsf(A[e])  * (1.0f + fabsf(ya[e]))
                                      + fabsf(Bc[e]) * (1.0f + fabsf(xa[e])));
                float yh = (A[e]  > 0.0f) ? pyhi : pylo;
                float yl = (A[e]  > 0.0f) ? pylo : pyhi;
                float xh = (Bc[e] > 0.0f) ? pxhi : pxlo;
                float xl = (Bc[e] > 0.0f) ? pxlo : pxhi;
                float hi = A[e] * yh + Bc[e] * xh + C;
                float lo = A[e] * yl + Bc[e] * xl + C;
                killneg = killneg || (hi < -err);
                killpos = killpos || (lo >  err);
            }
        }
        bool skip = killneg && killpos;

        // Phase 2: survivors broadcast from the holding lane via v_readlane
        // (k is wave-uniform) — no LDS-pipe ops, no memory ops.
        unsigned long long m = __ballot((int)!skip);
        while (m) {
            if (__all((int)covered)) break;
            int k = __ffsll((long long)m) - 1;
            m &= m - 1;
            float bx0 = bcast_lane(x0, k), by0 = bcast_lane(y0, k);
            float bx1 = bcast_lane(x1, k), by1 = bcast_lane(y1, k);
            float bx2 = bcast_lane(x2, k), by2 = bcast_lane(y2, k);
            // Broadcast lane-k's diffs directly: identical f32 values to the
            // reference's (x1-x0) etc. (same inputs, same op, computed lane k).
            float bd01x = bcast_lane(d01x, k), bd01y = bcast_lane(d01y, k);
            float bd12x = bcast_lane(d12x, k), bd12y = bcast_lane(d12y, k);
            float bd20x = bcast_lane(d20x, k), bd20y = bcast_lane(d20y, k);
            // e = (x1-x0)*(py-y0) - (y1-y0)*(px-x0): mul, mul, sub — no FMA
            float e0 = bd01x * (py - by0) - bd01y * (px - bx0);
            float e1 = bd12x * (py - by1) - bd12y * (px - bx1);
            float e2 = bd20x * (py - by2) - bd20y * (px - bx2);
            float mn = fminf(fminf(e0, e1), e2);
            float mx = fmaxf(fmaxf(e0, e1), e2);
            covered = covered || (mn >= 0.0f) || (mx <= 0.0f);
        }
    }

    float val = covered ? 1.0f : 0.0f;
    size_t o = ((size_t)(b * HW + py_i) * HW + px_i) * 3;
    out[o + 0] = val;
    out[o + 1] = val;
    out[o + 2] = val;
}

extern "C" void kernel_launch(void* const* d_in, const int* in_sizes, int n_in,
                              void* d_out, int out_size, void* d_ws, size_t ws_size,
                              hipStream_t stream) {
    const float* verts = (const float*)d_in[0];   // [2,4096,3] f32
    const int*   faces = (const int*)d_in[1];     // [2,4096,3] i32
    const float* R     = (const float*)d_in[2];   // [2,3,3]    f32
    const float* T     = (const float*)d_in[3];   // [2,3]      f32
    float*       out   = (float*)d_out;           // [2,256,256,3] f32

    float4* fxy4 = (float4*)d_ws;                        // 128 KiB
    float2* fxy2 = (float2*)(fxy4 + BATCH * FCOUNT);     // 64 KiB

    int nf = BATCH * FCOUNT;
    face_pack_kernel<<<(nf + 255) / 256, 256, 0, stream>>>(verts, faces, R, T,
                                                           fxy4, fxy2);

    dim3 grid(256, BATCH);
    raster_kernel<<<grid, 256, 0, stream>>>(fxy4, fxy2, out);
}